// Round 4
// baseline (4602.246 us; speedup 1.0000x reference)
//
#include <hip/hip_runtime.h>

#define TT 1024
#define BB 64
#define DD 512
#define HH 512
#define NG 4       // batch groups (16 batches each)
#define BPG 16
#define NS 32      // hidden slices (16 units each)
#define UPS 16
#define NTHR 256

typedef short s8v __attribute__((ext_vector_type(8)));
typedef float f4v __attribute__((ext_vector_type(4)));
typedef int i4v __attribute__((ext_vector_type(4)));

static __device__ __forceinline__ unsigned short f2bf(float f) {
  union { float f; unsigned int u; } v; v.f = f;
  unsigned int r = v.u + 0x7FFFu + ((v.u >> 16) & 1u);  // RNE
  return (unsigned short)(r >> 16);
}

// Coherent (L3) accesses: sc0 sc1 bypass L1+L2 — no compiler wbl2/inv.
static __device__ __forceinline__ i4v ld_b128_cohere(const void* p) {
  i4v r;
  asm volatile("global_load_dwordx4 %0, %1, off sc0 sc1"
               : "=v"(r) : "v"(p) : "memory");
  return r;
}
static __device__ __forceinline__ int ld_b32_cohere(const void* p) {
  int r;
  asm volatile("global_load_dword %0, %1, off sc0 sc1\n\t"
               "s_waitcnt vmcnt(0)"
               : "=v"(r) : "v"(p) : "memory");
  return r;
}
static __device__ __forceinline__ void st_b32_cohere(void* p, unsigned int v) {
  asm volatile("global_store_dword %0, %1, off sc0 sc1"
               :: "v"(p), "v"(v) : "memory");
}
static __device__ __forceinline__ unsigned int cvtpk_bf16(float lo, float hi) {
  unsigned int r;
  asm("v_cvt_pk_bf16_f32 %0, %1, %2" : "=v"(r) : "v"(lo), "v"(hi));
  return r;
}

__global__ void __launch_bounds__(256, 1) qlstm_init(int* flags) {
  st_b32_cohere(flags + threadIdx.x, 0u);   // flags[2][NG][NS] = 256 ints
}

// x-part GEMM for step t: A-frags straight from global fp32, result -> zpx.
static __device__ __forceinline__ void x_gemm(
    const float* __restrict__ X, int t, int b0, int n, int kg,
    const s8v* wreg0, const s8v* wreg1,
    float* __restrict__ zdst0, float* __restrict__ zdst1) {
  const float* Xb = X + ((size_t)t * BB + b0 + n) * DD + kg * 8;
  f4v a0 = {0.f, 0.f, 0.f, 0.f}, a1 = {0.f, 0.f, 0.f, 0.f};
#pragma unroll
  for (int kc = 0; kc < 16; ++kc) {
    const float4 xa = *(const float4*)(Xb + kc * 32);
    const float4 xb = *(const float4*)(Xb + kc * 32 + 4);
    union { s8v s; unsigned int d[4]; } af;
    af.d[0] = cvtpk_bf16(xa.x, xa.y);
    af.d[1] = cvtpk_bf16(xa.z, xa.w);
    af.d[2] = cvtpk_bf16(xb.x, xb.y);
    af.d[3] = cvtpk_bf16(xb.z, xb.w);
    a0 = __builtin_amdgcn_mfma_f32_16x16x32_bf16(af.s, wreg0[kc], a0, 0, 0, 0);
    a1 = __builtin_amdgcn_mfma_f32_16x16x32_bf16(af.s, wreg1[kc], a1, 0, 0, 0);
  }
#pragma unroll
  for (int i = 0; i < 4; ++i) { zdst0[i * 64] = a0[i]; zdst1[i * 64] = a1[i]; }
}

__global__ void __launch_bounds__(NTHR, 1) qlstm_main(
    const float* __restrict__ X,
    const float* __restrict__ Wf, const float* __restrict__ bfp,
    const float* __restrict__ Wi, const float* __restrict__ bip,
    const float* __restrict__ Wg, const float* __restrict__ bgp,
    const float* __restrict__ Wo, const float* __restrict__ bop,
    const float* __restrict__ phase,
    float* __restrict__ out, int* __restrict__ flags,
    unsigned short* __restrict__ hbuf) {
  // zpx[parity][uhalf][tile][i][lane] — lane-indexed stride-1: conflict-free.
  __shared__ float zpx[2][2][2][4][64];
  const int tid   = threadIdx.x;
  const int wv    = tid >> 6;
  const int lane  = tid & 63;
  const int n     = lane & 15;
  const int kg    = lane >> 4;
  const int group = blockIdx.x & (NG - 1);
  const int slice = blockIdx.x / NG;
  const int b0 = group * BPG;
  const int u0 = slice * UPS;
  const bool isH = (wv >= 2);
  const int uh = wv & 1;            // unit half: waves 0,2 -> 0; 1,3 -> 1

  // B-frag col packing (per wave, 2 tiles of 16 cols):
  //  tile0: n<8 -> (f, u0+uh*8+n), n>=8 -> (i, u0+uh*8+n-8)
  //  tile1: same units with (g, o). Waves 0,1: K rows 0..511 (x); 2,3: 512..1023 (h).
  const float* Wt0 = (n < 8) ? Wf : Wi;
  const float* Wt1 = (n < 8) ? Wg : Wo;
  const int wcol  = u0 + uh * 8 + (n & 7);
  const int krow0 = (isH ? 512 : 0) + kg * 8;
  s8v wreg0[16], wreg1[16];
#pragma unroll
  for (int kc = 0; kc < 16; ++kc) {
#pragma unroll
    for (int j = 0; j < 8; ++j) {
      const int row = krow0 + kc * 32 + j;
      wreg0[kc][j] = (short)f2bf(Wt0[(size_t)row * HH + wcol]);
      wreg1[kc][j] = (short)f2bf(Wt1[(size_t)row * HH + wcol]);
    }
  }

  if (!isH) {
    // ================= x-waves: off-critical-path producer =================
    x_gemm(X, 0, b0, n, kg, wreg0, wreg1,
           &zpx[0][uh][0][0][lane], &zpx[0][uh][1][0][lane]);
    __syncthreads();  // prologue handoff (zpx(0) ready)
    for (int t = 0; t < TT; ++t) {
      if (t + 1 < TT)
        x_gemm(X, t + 1, b0, n, kg, wreg0, wreg1,
               &zpx[(t + 1) & 1][uh][0][0][lane],
               &zpx[(t + 1) & 1][uh][1][0][lane]);
      asm volatile("s_waitcnt lgkmcnt(0)" ::: "memory");
      __builtin_amdgcn_sched_barrier(0);
      __builtin_amdgcn_s_barrier();            // barX
      __builtin_amdgcn_sched_barrier(0);
    }
  } else {
    // ================= h-waves: the critical path =================
    const int uu = u0 + uh * 8 + (n & 7);
    const float bz0 = bfp[uu] + phase[uu];
    const float bz1 = bip[uu] + phase[uu];
    const float bz2 = bgp[uu] + phase[uu];
    const float bz3 = bop[uu] + phase[uu];
    float cst[4] = {0.f, 0.f, 0.f, 0.f};
    int* myflag = flags + (uh * NG + group) * NS + slice;
    const int* pollp = flags + ((lane >> 5) * NG + group) * NS + (lane & 31);

    __syncthreads();  // prologue handoff
    for (int t = 0; t < TT; ++t) {
      // zpx(t) prefetch (written before previous barrier — safe)
      f4v px0, px1;
#pragma unroll
      for (int i = 0; i < 4; ++i) {
        px0[i] = zpx[t & 1][uh][0][i][lane];
        px1[i] = zpx[t & 1][uh][1][i][lane];
      }
      f4v a0 = {0.f, 0.f, 0.f, 0.f}, a1 = {0.f, 0.f, 0.f, 0.f};
      if (t > 0) {
        // poll both h-wave flag arrays of this group (64 flags, 1 load)
        for (;;) {
          const int v = ld_b32_cohere(pollp);
          if (__all(v >= t)) break;
          __builtin_amdgcn_s_sleep(1);   // R3 removed this -> L3 livelock
        }
        // h(t-1) directly in A-frag layout: lane (row=n, k=kg*8+kc*32+j)
        const unsigned short* hb = hbuf + (size_t)((t - 1) & 1) * BB * HH +
                                   (size_t)(b0 + n) * HH + kg * 8;
        i4v hf[16];
#pragma unroll
        for (int kc = 0; kc < 16; ++kc) hf[kc] = ld_b128_cohere(hb + kc * 32);
        // asm loads are opaque to the compiler: MUST drain before MFMAs
        // consume hf, and fence so reg-only MFMAs can't hoist above (rule #18)
        asm volatile("s_waitcnt vmcnt(0)" ::: "memory");
        __builtin_amdgcn_sched_barrier(0);
#pragma unroll
        for (int kc = 0; kc < 16; ++kc) {
          union { i4v i; s8v s; } af; af.i = hf[kc];
          a0 = __builtin_amdgcn_mfma_f32_16x16x32_bf16(af.s, wreg0[kc], a0, 0, 0, 0);
          a1 = __builtin_amdgcn_mfma_f32_16x16x32_bf16(af.s, wreg1[kc], a1, 0, 0, 0);
        }
      }
      // gates fully in-register: lane pair (n, n^8) holds {f,i} / {g,o}
      float hv[4];
#pragma unroll
      for (int i = 0; i < 4; ++i) {
        const float s0 = a0[i] + px0[i];
        const float s1 = a1[i] + px1[i];
        const float p0 = __shfl_xor(s0, 8);
        const float p1 = __shfl_xor(s1, 8);
        const bool lo = (n < 8);
        const float zf = (lo ? s0 : p0) + bz0;
        const float zi = (lo ? p0 : s0) + bz1;
        const float zg = (lo ? s1 : p1) + bz2;
        const float zo = (lo ? p1 : s1) + bz3;
        const float fg = 1.f / (1.f + __expf(-zf));
        const float ig = 1.f / (1.f + __expf(-zi));
        const float gg = 1.f - 2.f / (__expf(2.f * zg) + 1.f);
        const float og = 1.f / (1.f + __expf(-zo));
        cst[i] = fg * cst[i] + ig * gg;
        hv[i] = og * (1.f - 2.f / (__expf(2.f * cst[i]) + 1.f));
      }
      // publish h (packed bf16, coherent), then flag; out stores after flag
      float hn[4];
#pragma unroll
      for (int i = 0; i < 4; ++i) hn[i] = __shfl_down(hv[i], 1);
      unsigned short* hp = hbuf + (size_t)(t & 1) * BB * HH;
      if (n < 8 && !(n & 1)) {
#pragma unroll
        for (int i = 0; i < 4; ++i)
          st_b32_cohere(hp + (size_t)(b0 + 4 * kg + i) * HH + (u0 + uh * 8 + n),
                        cvtpk_bf16(hv[i], hn[i]));
      }
      asm volatile("s_waitcnt vmcnt(0)" ::: "memory");  // h stores acked
      if (lane == 0) st_b32_cohere(myflag, (unsigned int)(t + 1));
      if (n < 8) {
#pragma unroll
        for (int i = 0; i < 4; ++i)
          out[(size_t)t * BB * HH + (size_t)(b0 + 4 * kg + i) * HH + uu] = hv[i];
        if (t == TT - 1) {
#pragma unroll
          for (int i = 0; i < 4; ++i) {
            out[(size_t)TT * BB * HH + (size_t)(b0 + 4 * kg + i) * HH + uu] = hv[i];
            out[(size_t)TT * BB * HH + BB * HH +
                (size_t)(b0 + 4 * kg + i) * HH + uu] = cst[i];
          }
        }
      }
      __builtin_amdgcn_sched_barrier(0);
      __builtin_amdgcn_s_barrier();            // barX (off critical path here)
      __builtin_amdgcn_sched_barrier(0);
    }
  }
}

extern "C" void kernel_launch(void* const* d_in, const int* in_sizes, int n_in,
                              void* d_out, int out_size, void* d_ws,
                              size_t ws_size, hipStream_t stream) {
  const float* X   = (const float*)d_in[0];
  const float* Wf  = (const float*)d_in[1];
  const float* bfp = (const float*)d_in[2];
  const float* Wi  = (const float*)d_in[3];
  const float* bip = (const float*)d_in[4];
  const float* Wg  = (const float*)d_in[5];
  const float* bgp = (const float*)d_in[6];
  const float* Wo  = (const float*)d_in[7];
  const float* bop = (const float*)d_in[8];
  const float* ph  = (const float*)d_in[9];
  float* out = (float*)d_out;

  // ws: [0,1KB) flags[2][4][32]; [4KB, 4KB+128KB) bf16 h double-buffer
  int* flags = (int*)d_ws;
  unsigned short* hbuf = (unsigned short*)((char*)d_ws + 4096);

  qlstm_init<<<1, 256, 0, stream>>>(flags);
  qlstm_main<<<NG * NS, NTHR, 0, stream>>>(X, Wf, bfp, Wi, bip, Wg, bgp, Wo,
                                           bop, ph, out, flags, hbuf);
}